// Round 6
// baseline (259.328 us; speedup 1.0000x reference)
//
#include <hip/hip_runtime.h>
#include <math.h>

#define N_NODES 50000
#define N_EDGES 800000
#define IN_DIM 128
#define OUT_DIM 16
#define N_HEADS 4
#define HID 64            // N_HEADS*OUT_DIM
#define AW_COLS 33        // 2*OUT_DIM+1
#define GN 32             // nodes per block (gemm); R26
#define GEMM_BLK ((N_NODES + GN - 1) / GN)             // 1563
#define HE 16             // edges per thread (hist)
#define HBLK ((N_EDGES + 256 * HE - 1) / (256 * HE))   // 196
#define MAXDEG 64         // padded bucket width; deg~Poisson(16), max~35 (12 sigma margin)

// LDS plan (R26): staging sN = GN*128*4 = 16384 B, dead after barrier2;
// overlay: scr (2 grp * 64 ln * 17 dbl = 17408 B) + h_lds (GN*64*4 = 8192 B)
// = 25600 B -> 6 blocks/CU (153600 <= 163840), 24 waves/CU (75%).
#define SCR_DOUBLES (2 * 64 * 17)          // 2176
#define SMEM_DOUBLES 3200                  // 25600 B

// R26: W out of LDS + occupancy. R25 counters showed VALU 35% / DS ~35% /
// HBM 15% at Occ 35% -- no pipe saturated => latency-bound at 4 blocks/CU.
// R24 proved "more waves at MORE traffic" loses; this is more waves at LESS
// traffic: W (32KB, grid-uniform, exactly L1-sized) read from global via the
// idle VMEM pipe -- deletes sW + its staging; GN=32 with 2x2-way k-split
// amortizes xq reads over 16 nodes (DS/node -55%). LDS 40960->25600 ->
// 6 blocks/CU. Numerics: f64 products exact; k-order (b + lowK + highK),
// same 1e-16 reorder class as R25 (absmax stayed 0.015625).
// f64 GEMM LOCKED (near-one-hot softmax, argmax flips vs f32 ref).
// NOTE (R7/R8): f64 MFMA produced zeros -- shelved.
// NOTE (R10/R14): per-node X operand reads from global lose to LDS staging
// (W is different: grid-uniform, L1-resident).
// NOTE (R24): more waves without less traffic regresses; don't retry.
__global__ __launch_bounds__(256, 6) void gemm_hist(
    const float* __restrict__ nodes, const float* __restrict__ W,
    const float* __restrict__ b, const float* __restrict__ attn_W,
    const float* __restrict__ attn_b, const float* __restrict__ edges,
    float* __restrict__ h, double* __restrict__ z_src, double* __restrict__ z_dst,
    const int* __restrict__ senders, const int* __restrict__ receivers,
    int* __restrict__ counts, int* __restrict__ srt_padded,
    double* __restrict__ Ssum) {
    __shared__ double smem_d[SMEM_DOUBLES];    // 25600 B, multi-phase overlay
    float* sN = (float*)smem_d;                // staging, rotated (phase 1)
    int t = threadIdx.x;

    if (blockIdx.x < HBLK) {
        // ---------------- hist + direct bucket-scatter (R17) ----------------
        double* red = smem_d;
        int base = blockIdx.x * 256 * HE + t;
        double sp = 0.0;
        #pragma unroll
        for (int j = 0; j < HE; ++j) {
            int e = base + j * 256;
            if (e < N_EDGES) {
                int r = receivers[e];
                int rank = atomicAdd(&counts[r], 1);            // 0..deg-1
                if (rank < MAXDEG)
                    srt_padded[r * MAXDEG + rank] = senders[e];
                sp += (double)edges[senders[e]];
            }
        }
        red[t] = sp;
        __syncthreads();
        for (int off = 128; off > 0; off >>= 1) {
            if (t < off) red[t] += red[t + off];
            __syncthreads();
        }
        if (t == 0) atomicAdd(Ssum, red[0]);
    } else {
        // ------ gemm: GN=32, 4x4 lane tile, 2 groups x 2-way k-split ------
        int node0 = (blockIdx.x - HBLK) * GN;
        for (int i4 = t; i4 < GN * IN_DIM / 4; i4 += 256) {    // 1024 quads, rotated
            int ln = i4 >> 5, kq = i4 & 31;
            int n = node0 + ln;
            float4 v = (n < N_NODES) ? ((const float4*)nodes)[(long long)n * (IN_DIM / 4) + kq]
                                     : make_float4(0.f, 0.f, 0.f, 0.f);
            *(float4*)&sN[ln * IN_DIM + (((kq + ln) & 31) << 2)] = v;
        }
        __syncthreads();                   // barrier 1

        int w = t >> 6, l = t & 63;
        int g = w >> 1, kw = w & 1;        // group (16 nodes), k-half
        int og = l & 15;                   // outputs og + 16j, j=0..3
        int ng = l >> 4;                   // nodes   g*16 + ng + 4i, i=0..3
        int kbase = kw * 16;               // k-quads [kbase, kbase+16)

        double acc[4][4];                  // [j][i]
        #pragma unroll
        for (int j = 0; j < 4; ++j)
            #pragma unroll
            for (int i = 0; i < 4; ++i) acc[j][i] = 0.0;

        const float4* Wq = (const float4*)W;   // [64][32] quads, L1-resident
        #pragma unroll
        for (int s = 0; s < 16; ++s) {
            int kq = kbase + s;
            float4 wq[4], xq[4];
            #pragma unroll
            for (int j = 0; j < 4; ++j)
                wq[j] = Wq[(og + 16 * j) * (IN_DIM / 4) + kq];   // VMEM pipe
            #pragma unroll
            for (int i = 0; i < 4; ++i) {
                int ln = g * 16 + ng + 4 * i;
                xq[i] = *(const float4*)&sN[ln * IN_DIM + (((kq + ln) & 31) << 2)];
            }
            #pragma unroll
            for (int j = 0; j < 4; ++j) {
                double wx = (double)wq[j].x, wy = (double)wq[j].y;
                double wz = (double)wq[j].z, ww = (double)wq[j].w;
                #pragma unroll
                for (int i = 0; i < 4; ++i) {
                    double nx = (double)xq[i].x, ny = (double)xq[i].y;
                    double nz = (double)xq[i].z, nw = (double)xq[i].w;
                    acc[j][i] += wx * nx; acc[j][i] += wy * ny;
                    acc[j][i] += wz * nz; acc[j][i] += ww * nw;
                }
            }
        }
        __syncthreads();                   // barrier 2: sN reads done

        // ---- k-reduction: kw=1 waves dump, kw=0 waves sum (per group) ----
        double* scr = smem_d;              // overlays dead sN
        float* h_lds = (float*)(smem_d + SCR_DOUBLES);   // byte 17408..25600
        if (kw == 1) {
            double* dst = &scr[(g * 64 + l) * 17];
            #pragma unroll
            for (int j = 0; j < 4; ++j)
                #pragma unroll
                for (int i = 0; i < 4; ++i) dst[j * 4 + i] = acc[j][i];
        }
        __syncthreads();                   // barrier 3
        if (kw == 0) {
            const double* src = &scr[(g * 64 + l) * 17];
            #pragma unroll
            for (int j = 0; j < 4; ++j) {
                double bj = (double)b[og + 16 * j];
                #pragma unroll
                for (int i = 0; i < 4; ++i) {
                    double sum = bj + acc[j][i] + src[j * 4 + i];
                    h_lds[(g * 16 + ng + 4 * i) * HID + og + 16 * j] = (float)sum;
                }
            }
        }
        __syncthreads();                   // barrier 4

        // ---- epilogue: R21 z layout/order verbatim; 4 nodes per lane-half ----
        int half = l >> 5;
        int o2 = l & 31;
        int nwbase = w * 8 + half * 4;
        int hd0 = o2 >> 4, d = o2 & 15;
        int hd1 = hd0 + 2;
        double aw00 = (double)attn_W[hd0 * AW_COLS + d];
        double aw01 = (double)attn_W[hd0 * AW_COLS + OUT_DIM + d];
        double aw10 = (double)attn_W[hd1 * AW_COLS + d];
        double aw11 = (double)attn_W[hd1 * AW_COLS + OUT_DIM + d];
        double wE0 = (double)attn_W[hd0 * AW_COLS + 2 * OUT_DIM];
        double wE1 = (double)attn_W[hd1 * AW_COLS + 2 * OUT_DIM];
        double bb0 = (double)attn_b[hd0], bb1 = (double)attn_b[hd1];
        #pragma unroll
        for (int j = 0; j < 4; ++j) {
            int nl = nwbase + j;
            int n = node0 + nl;
            float hf0 = h_lds[nl * HID + o2];
            float hf1 = h_lds[nl * HID + o2 + 32];
            double c00 = (double)hf0 * aw00;   // a_src part, head hd0
            double c01 = (double)hf0 * aw01;   // a_dst part, head hd0
            double c10 = (double)hf1 * aw10;   // a_src part, head hd1
            double c11 = (double)hf1 * aw11;   // a_dst part, head hd1
            #pragma unroll
            for (int k = 1; k <= 8; k <<= 1) {
                c00 += __shfl_xor(c00, k, 64);
                c01 += __shfl_xor(c01, k, 64);
                c10 += __shfl_xor(c10, k, 64);
                c11 += __shfl_xor(c11, k, 64);
            }
            if (n < N_NODES && d == 0) {
                double se = (double)edges[n];
                z_src[n * N_HEADS + hd0] = c00 + se * wE0;
                z_dst[n * N_HEADS + hd0] = c01 + bb0;
                z_src[n * N_HEADS + hd1] = c10 + se * wE1;
                z_dst[n * N_HEADS + hd1] = c11 + bb1;
            }
        }
        // coalesced h write: 2048 floats = 512 quads, 2 per thread, guarded
        {
            const float4* hq = (const float4*)h_lds;
            int i0 = t, i1 = t + 256;
            if (node0 + (i0 >> 4) < N_NODES)
                ((float4*)h)[(long long)node0 * (HID / 4) + i0] = hq[i0];
            if (node0 + (i1 >> 4) < N_NODES)
                ((float4*)h)[(long long)node0 * (HID / 4) + i1] = hq[i1];
        }
    }
}

// R22 form (best known, FROZEN). TWO nodes per wave, phases pairwise
// interleaved; near-one-hot softmax -> ballot loop does ~1-4 gathers/node
// (R23's dense rewrite did 16x traffic, +12us -- don't retry).
__global__ __launch_bounds__(256, 8) void node_fused(
    const float* __restrict__ h, const double* __restrict__ z_src,
    const double* __restrict__ z_dst,
    const int* __restrict__ srt_padded, const int* __restrict__ counts,
    const double* __restrict__ Ssum, float* __restrict__ out) {
    int w = threadIdx.x >> 6;
    int lane = threadIdx.x & 63;
    int nA = blockIdx.x * 8 + w * 2;     // grid exact: 6250*8 = 50000
    int nB = nA + 1;
    int hd = lane >> 4, q = lane & 15;

    int degA = counts[nA]; if (degA > MAXDEG) degA = MAXDEG;
    int degB = counts[nB]; if (degB > MAXDEG) degB = MAXDEG;
    double S = 4.0 * Ssum[0];                       // sent_e tiled over heads
    double zdA = z_dst[nA * N_HEADS + hd];
    double zdB = z_dst[nB * N_HEADS + hd];

    // ---- edge-id gather (both nodes issued before use) ----
    int sA[4], sB[4];
    #pragma unroll
    for (int j = 0; j < 4; ++j) {
        int ei = q + 16 * j;
        sA[j] = (ei < degA) ? srt_padded[nA * MAXDEG + ei] : 0;
        sB[j] = (ei < degB) ? srt_padded[nB * MAXDEG + ei] : 0;
    }
    // ---- z_src scatter-gather + leaky (f64, then round) — bit-exact ----
    float yA[4], yB[4];
    #pragma unroll
    for (int j = 0; j < 4; ++j) {
        int ei = q + 16 * j;
        yA[j] = -INFINITY;
        yB[j] = -INFINITY;
        if (ei < degA) {
            double yy = z_src[sA[j] * N_HEADS + hd] + zdA;
            yy = yy > 0.0 ? yy : 0.01 * yy;
            yA[j] = (float)yy;
        }
        if (ei < degB) {
            double yy = z_src[sB[j] * N_HEADS + hd] + zdB;
            yy = yy > 0.0 ? yy : 0.01 * yy;
            yB[j] = (float)yy;
        }
    }
    // ---- per-head max: two butterfly chains interleaved ----
    float mA = fmaxf(fmaxf(yA[0], yA[1]), fmaxf(yA[2], yA[3]));
    float mB = fmaxf(fmaxf(yB[0], yB[1]), fmaxf(yB[2], yB[3]));
    #pragma unroll
    for (int k = 1; k <= 8; k <<= 1) {
        mA = fmaxf(mA, __shfl_xor(mA, k, 64));
        mB = fmaxf(mB, __shfl_xor(mB, k, 64));
    }
    // ---- exp + denominator (same expression order as R21) ----
    float evA[4], evB[4];
    float dA = 0.f, dB = 0.f;
    #pragma unroll
    for (int j = 0; j < 4; ++j) {
        evA[j] = (yA[j] == -INFINITY) ? 0.f
               : __expf((float)(S * ((double)yA[j] - (double)mA)));
        dA += evA[j];
        evB[j] = (yB[j] == -INFINITY) ? 0.f
               : __expf((float)(S * ((double)yB[j] - (double)mB)));
        dB += evB[j];
    }
    #pragma unroll
    for (int k = 1; k <= 8; k <<= 1) {
        dA += __shfl_xor(dA, k, 64);
        dB += __shfl_xor(dB, k, 64);
    }
    // ---- ballot-compressed accumulate, node A then node B (order preserved) ----
    float accA = 0.f;
    #pragma unroll
    for (int j = 0; j < 4; ++j) {
        unsigned long long mk = __ballot(evA[j] != 0.f);
        unsigned um = (unsigned)((mk | (mk >> 16) | (mk >> 32) | (mk >> 48)) & 0xFFFFull);
        while (um) {
            int qq = __builtin_ctz(um);
            um &= um - 1;
            int src = (lane & 48) | qq;                 // own head's copy
            float evv = __shfl(evA[j], src, 64);
            int sj = __shfl(sA[j], src, 64);
            if (evv != 0.f)
                accA = fmaf(evv, h[sj * HID + lane], accA);
        }
    }
    float accB = 0.f;
    #pragma unroll
    for (int j = 0; j < 4; ++j) {
        unsigned long long mk = __ballot(evB[j] != 0.f);
        unsigned um = (unsigned)((mk | (mk >> 16) | (mk >> 32) | (mk >> 48)) & 0xFFFFull);
        while (um) {
            int qq = __builtin_ctz(um);
            um &= um - 1;
            int src = (lane & 48) | qq;
            float evv = __shfl(evB[j], src, 64);
            int sj = __shfl(sB[j], src, 64);
            if (evv != 0.f)
                accB = fmaf(evv, h[sj * HID + lane], accB);
        }
    }
    float rA = (dA > 0.f) ? accA / dA : 0.f;
    float rB = (dB > 0.f) ? accB / dB : 0.f;
    out[nA * HID + lane] = rA > 0.f ? rA : 0.01f * rA;
    out[nB * HID + lane] = rB > 0.f ? rB : 0.01f * rB;
}

static inline char* ws_take(char*& p, size_t bytes) {
    char* cur = p;
    p += (bytes + 255) & ~(size_t)255;   // keep every buffer 256B-aligned
    return cur;
}

extern "C" void kernel_launch(void* const* d_in, const int* in_sizes, int n_in,
                              void* d_out, int out_size, void* d_ws, size_t ws_size,
                              hipStream_t stream) {
    const float* nodes     = (const float*)d_in[0];
    const float* edges     = (const float*)d_in[1];
    const int*   senders   = (const int*)d_in[2];
    const int*   receivers = (const int*)d_in[3];
    const float* W         = (const float*)d_in[4];
    const float* b         = (const float*)d_in[5];
    const float* attn_W    = (const float*)d_in[6];
    const float* attn_b    = (const float*)d_in[7];
    float* out = (float*)d_out;

    char* p = (char*)d_ws;
    float*  h          = (float*)ws_take(p, sizeof(float) * N_NODES * HID);
    double* z_src      = (double*)ws_take(p, sizeof(double) * N_NODES * N_HEADS);
    double* z_dst      = (double*)ws_take(p, sizeof(double) * N_NODES * N_HEADS);
    int*    counts     = (int*)ws_take(p, sizeof(int) * N_NODES);   // contiguous with
    char*   zpad       = ws_take(p, 256);                           // Ssum: one memset
    double* Ssum       = (double*)zpad;
    int*    srt_padded = (int*)ws_take(p, sizeof(int) * (size_t)N_NODES * MAXDEG);

    // counts (256B-rounded) + the Ssum pad in one memset; srt_padded needs no init
    hipMemsetAsync(counts, 0, ((sizeof(int) * N_NODES + 255) & ~(size_t)255) + 256, stream);

    gemm_hist<<<HBLK + GEMM_BLK, 256, 0, stream>>>(
        nodes, W, b, attn_W, attn_b, edges, h, z_src, z_dst,
        senders, receivers, counts, srt_padded, Ssum);
    node_fused<<<(N_NODES + 7) / 8, 256, 0, stream>>>(
        h, z_src, z_dst, srt_padded, counts, Ssum, out);
}

// Round 7
// 176.043 us; speedup vs baseline: 1.4731x; 1.4731x over previous
//
#include <hip/hip_runtime.h>
#include <math.h>

#define N_NODES 50000
#define N_EDGES 800000
#define IN_DIM 128
#define OUT_DIM 16
#define N_HEADS 4
#define HID 64            // N_HEADS*OUT_DIM
#define AW_COLS 33        // 2*OUT_DIM+1
#define GN 16             // nodes per block (gemm); 3125*16 = 50000 exact
#define GEMM_BLK ((N_NODES + GN - 1) / GN)             // 3125
#define HE 16             // edges per thread (hist)
#define HBLK ((N_EDGES + 256 * HE - 1) / (256 * HE))   // 196
#define MAXDEG 64         // padded bucket width; deg~Poisson(16), max~35 (12 sigma margin)

// LDS plan (R27): phase1 staging sN = 16*128*4 = 8192 B (overlays smem start,
// dead at barrier2); phase2 scr = 3*64*17 dbl = 26112 B + h_lds = 16*64*4 =
// 4096 B -> total 30208 B -> 5 blocks/CU (151040 <= 163840), 20 waves/CU.
#define SCR_DOUBLES (3 * 64 * 17)          // 3264
#define SMEM_DOUBLES (SCR_DOUBLES + 512)   // + h_lds(4096B) = 30208 B

// R27 = R25 gemm + ONE change: W read from global (L1-resident, 32KB,
// grid-uniform; 16 rows x 16B per wq read -- cache-friendly, unlike R10/R14's
// per-node X reads) -> deletes sW + its staging, LDS 40960->30208 -> 5
// blocks/CU. launch_bounds stays (256,4): VGPR cap 128.
// R26 POST-MORTEM (don't repeat): __launch_bounds__(256,6) capped VGPR at 40
// -> acc[4][4] f64 spilled to scratch -> +250MB/dispatch global traffic,
// VALUBusy 13%, gemm 160us. Never set waves-arg beyond 512/waves >= 1.5x the
// known VGPR need. R26 also changed 4 variables at once -- spill polluted all.
// Numerics: FMA/k-split/reduction order identical to R25 -> h bit-identical.
// f64 GEMM LOCKED (near-one-hot softmax, argmax flips vs f32 ref).
// NOTE (R7/R8): f64 MFMA produced zeros -- shelved.
// NOTE (R24): more waves without less traffic regresses; don't retry.
__global__ __launch_bounds__(256, 4) void gemm_hist(
    const float* __restrict__ nodes, const float* __restrict__ W,
    const float* __restrict__ b, const float* __restrict__ attn_W,
    const float* __restrict__ attn_b, const float* __restrict__ edges,
    float* __restrict__ h, double* __restrict__ z_src, double* __restrict__ z_dst,
    const int* __restrict__ senders, const int* __restrict__ receivers,
    int* __restrict__ counts, int* __restrict__ srt_padded,
    double* __restrict__ Ssum) {
    __shared__ double smem_d[SMEM_DOUBLES];    // 30208 B, multi-phase overlay
    float* sN = (float*)smem_d;                // phase-1 staging, rotated
    int t = threadIdx.x;

    if (blockIdx.x < HBLK) {
        // ---------------- hist + direct bucket-scatter (R17) ----------------
        double* red = smem_d;
        int base = blockIdx.x * 256 * HE + t;
        double sp = 0.0;
        #pragma unroll
        for (int j = 0; j < HE; ++j) {
            int e = base + j * 256;
            if (e < N_EDGES) {
                int r = receivers[e];
                int rank = atomicAdd(&counts[r], 1);            // 0..deg-1
                if (rank < MAXDEG)
                    srt_padded[r * MAXDEG + rank] = senders[e];
                sp += (double)edges[senders[e]];
            }
        }
        red[t] = sp;
        __syncthreads();
        for (int off = 128; off > 0; off >>= 1) {
            if (t < off) red[t] += red[t + off];
            __syncthreads();
        }
        if (t == 0) atomicAdd(Ssum, red[0]);
    } else {
        // -------- gemm body: 4x4 lane tile, 4-way k-split, GN=16 --------
        int node0 = (blockIdx.x - HBLK) * GN;
        for (int i4 = t; i4 < GN * IN_DIM / 4; i4 += 256) {    // 512 quads, rotated
            int ln = i4 >> 5, kq = i4 & 31;
            float4 v = ((const float4*)nodes)[(long long)(node0 + ln) * (IN_DIM / 4) + kq];
            *(float4*)&sN[ln * IN_DIM + (((kq + ln) & 31) << 2)] = v;
        }
        __syncthreads();                   // barrier 1

        int w = t >> 6, l = t & 63;
        int og = l & 15;                   // outputs og + 16j, j=0..3
        int ng = l >> 4;                   // nodes   ng + 4i,  i=0..3
        int kbase = w * 8;                 // this wave's kq range [kbase, kbase+8)

        double acc[4][4];                  // [j][i]
        #pragma unroll
        for (int j = 0; j < 4; ++j)
            #pragma unroll
            for (int i = 0; i < 4; ++i) acc[j][i] = 0.0;

        const float4* Wq = (const float4*)W;   // [64][32] quads, L1-resident
        #pragma unroll
        for (int s = 0; s < 8; ++s) {
            int kq = kbase + s;
            float4 wq[4], xq[4];
            #pragma unroll
            for (int j = 0; j < 4; ++j)
                wq[j] = Wq[(og + 16 * j) * (IN_DIM / 4) + kq];   // VMEM pipe
            #pragma unroll
            for (int i = 0; i < 4; ++i) {
                int n = ng + 4 * i;
                xq[i] = *(const float4*)&sN[n * IN_DIM + (((kq + n) & 31) << 2)];
            }
            #pragma unroll
            for (int j = 0; j < 4; ++j) {
                double wx = (double)wq[j].x, wy = (double)wq[j].y;
                double wz = (double)wq[j].z, ww = (double)wq[j].w;
                #pragma unroll
                for (int i = 0; i < 4; ++i) {
                    double nx = (double)xq[i].x, ny = (double)xq[i].y;
                    double nz = (double)xq[i].z, nw = (double)xq[i].w;
                    acc[j][i] += wx * nx; acc[j][i] += wy * ny;
                    acc[j][i] += wz * nz; acc[j][i] += ww * nw;
                }
            }
        }
        __syncthreads();                   // barrier 2: sN reads done

        // ---- k-reduction: waves 1-3 dump partials, wave 0 sums ----
        double* scr = smem_d;              // overlays dead sN
        float* h_lds = (float*)(smem_d + SCR_DOUBLES);
        if (w > 0) {
            double* dst = &scr[((w - 1) * 64 + l) * 17];
            #pragma unroll
            for (int j = 0; j < 4; ++j)
                #pragma unroll
                for (int i = 0; i < 4; ++i) dst[j * 4 + i] = acc[j][i];
        }
        __syncthreads();                   // barrier 3
        if (w == 0) {
            #pragma unroll
            for (int j = 0; j < 4; ++j) {
                double bj = (double)b[og + 16 * j];
                #pragma unroll
                for (int i = 0; i < 4; ++i) {
                    double sum = bj + acc[j][i];
                    sum += scr[(0 * 64 + l) * 17 + j * 4 + i];
                    sum += scr[(1 * 64 + l) * 17 + j * 4 + i];
                    sum += scr[(2 * 64 + l) * 17 + j * 4 + i];
                    h_lds[(ng + 4 * i) * HID + og + 16 * j] = (float)sum;
                }
            }
        }
        __syncthreads();                   // barrier 4

        // ---- epilogue: R21 layout/order verbatim, h values from h_lds ----
        int half = l >> 5;
        int o2 = l & 31;
        int nwbase = w * 4 + half * 2;
        int hd0 = o2 >> 4, d = o2 & 15;
        int hd1 = hd0 + 2;
        double aw00 = (double)attn_W[hd0 * AW_COLS + d];
        double aw01 = (double)attn_W[hd0 * AW_COLS + OUT_DIM + d];
        double aw10 = (double)attn_W[hd1 * AW_COLS + d];
        double aw11 = (double)attn_W[hd1 * AW_COLS + OUT_DIM + d];
        double wE0 = (double)attn_W[hd0 * AW_COLS + 2 * OUT_DIM];
        double wE1 = (double)attn_W[hd1 * AW_COLS + 2 * OUT_DIM];
        double bb0 = (double)attn_b[hd0], bb1 = (double)attn_b[hd1];
        #pragma unroll
        for (int j = 0; j < 2; ++j) {
            int nl = nwbase + j;
            int n = node0 + nl;            // always < 50000 (exact tiling)
            float hf0 = h_lds[nl * HID + o2];
            float hf1 = h_lds[nl * HID + o2 + 32];
            double c00 = (double)hf0 * aw00;   // a_src part, head hd0
            double c01 = (double)hf0 * aw01;   // a_dst part, head hd0
            double c10 = (double)hf1 * aw10;   // a_src part, head hd1
            double c11 = (double)hf1 * aw11;   // a_dst part, head hd1
            #pragma unroll
            for (int k = 1; k <= 8; k <<= 1) {
                c00 += __shfl_xor(c00, k, 64);
                c01 += __shfl_xor(c01, k, 64);
                c10 += __shfl_xor(c10, k, 64);
                c11 += __shfl_xor(c11, k, 64);
            }
            if (d == 0) {
                double se = (double)edges[n];
                z_src[n * N_HEADS + hd0] = c00 + se * wE0;
                z_dst[n * N_HEADS + hd0] = c01 + bb0;
                z_src[n * N_HEADS + hd1] = c10 + se * wE1;
                z_dst[n * N_HEADS + hd1] = c11 + bb1;
            }
        }
        // coalesced h write: block's h region is contiguous (1024 floats)
        ((float4*)h)[(long long)node0 * (HID / 4) + t] = ((const float4*)h_lds)[t];
    }
}

// R22 form (best known, FROZEN). TWO nodes per wave, phases pairwise
// interleaved; near-one-hot softmax -> ballot loop does ~1-4 gathers/node
// (R23's dense rewrite did 16x traffic, +12us -- don't retry).
__global__ __launch_bounds__(256, 8) void node_fused(
    const float* __restrict__ h, const double* __restrict__ z_src,
    const double* __restrict__ z_dst,
    const int* __restrict__ srt_padded, const int* __restrict__ counts,
    const double* __restrict__ Ssum, float* __restrict__ out) {
    int w = threadIdx.x >> 6;
    int lane = threadIdx.x & 63;
    int nA = blockIdx.x * 8 + w * 2;     // grid exact: 6250*8 = 50000
    int nB = nA + 1;
    int hd = lane >> 4, q = lane & 15;

    int degA = counts[nA]; if (degA > MAXDEG) degA = MAXDEG;
    int degB = counts[nB]; if (degB > MAXDEG) degB = MAXDEG;
    double S = 4.0 * Ssum[0];                       // sent_e tiled over heads
    double zdA = z_dst[nA * N_HEADS + hd];
    double zdB = z_dst[nB * N_HEADS + hd];

    // ---- edge-id gather (both nodes issued before use) ----
    int sA[4], sB[4];
    #pragma unroll
    for (int j = 0; j < 4; ++j) {
        int ei = q + 16 * j;
        sA[j] = (ei < degA) ? srt_padded[nA * MAXDEG + ei] : 0;
        sB[j] = (ei < degB) ? srt_padded[nB * MAXDEG + ei] : 0;
    }
    // ---- z_src scatter-gather + leaky (f64, then round) — bit-exact ----
    float yA[4], yB[4];
    #pragma unroll
    for (int j = 0; j < 4; ++j) {
        int ei = q + 16 * j;
        yA[j] = -INFINITY;
        yB[j] = -INFINITY;
        if (ei < degA) {
            double yy = z_src[sA[j] * N_HEADS + hd] + zdA;
            yy = yy > 0.0 ? yy : 0.01 * yy;
            yA[j] = (float)yy;
        }
        if (ei < degB) {
            double yy = z_src[sB[j] * N_HEADS + hd] + zdB;
            yy = yy > 0.0 ? yy : 0.01 * yy;
            yB[j] = (float)yy;
        }
    }
    // ---- per-head max: two butterfly chains interleaved ----
    float mA = fmaxf(fmaxf(yA[0], yA[1]), fmaxf(yA[2], yA[3]));
    float mB = fmaxf(fmaxf(yB[0], yB[1]), fmaxf(yB[2], yB[3]));
    #pragma unroll
    for (int k = 1; k <= 8; k <<= 1) {
        mA = fmaxf(mA, __shfl_xor(mA, k, 64));
        mB = fmaxf(mB, __shfl_xor(mB, k, 64));
    }
    // ---- exp + denominator (same expression order as R21) ----
    float evA[4], evB[4];
    float dA = 0.f, dB = 0.f;
    #pragma unroll
    for (int j = 0; j < 4; ++j) {
        evA[j] = (yA[j] == -INFINITY) ? 0.f
               : __expf((float)(S * ((double)yA[j] - (double)mA)));
        dA += evA[j];
        evB[j] = (yB[j] == -INFINITY) ? 0.f
               : __expf((float)(S * ((double)yB[j] - (double)mB)));
        dB += evB[j];
    }
    #pragma unroll
    for (int k = 1; k <= 8; k <<= 1) {
        dA += __shfl_xor(dA, k, 64);
        dB += __shfl_xor(dB, k, 64);
    }
    // ---- ballot-compressed accumulate, node A then node B (order preserved) ----
    float accA = 0.f;
    #pragma unroll
    for (int j = 0; j < 4; ++j) {
        unsigned long long mk = __ballot(evA[j] != 0.f);
        unsigned um = (unsigned)((mk | (mk >> 16) | (mk >> 32) | (mk >> 48)) & 0xFFFFull);
        while (um) {
            int qq = __builtin_ctz(um);
            um &= um - 1;
            int src = (lane & 48) | qq;                 // own head's copy
            float evv = __shfl(evA[j], src, 64);
            int sj = __shfl(sA[j], src, 64);
            if (evv != 0.f)
                accA = fmaf(evv, h[sj * HID + lane], accA);
        }
    }
    float accB = 0.f;
    #pragma unroll
    for (int j = 0; j < 4; ++j) {
        unsigned long long mk = __ballot(evB[j] != 0.f);
        unsigned um = (unsigned)((mk | (mk >> 16) | (mk >> 32) | (mk >> 48)) & 0xFFFFull);
        while (um) {
            int qq = __builtin_ctz(um);
            um &= um - 1;
            int src = (lane & 48) | qq;
            float evv = __shfl(evB[j], src, 64);
            int sj = __shfl(sB[j], src, 64);
            if (evv != 0.f)
                accB = fmaf(evv, h[sj * HID + lane], accB);
        }
    }
    float rA = (dA > 0.f) ? accA / dA : 0.f;
    float rB = (dB > 0.f) ? accB / dB : 0.f;
    out[nA * HID + lane] = rA > 0.f ? rA : 0.01f * rA;
    out[nB * HID + lane] = rB > 0.f ? rB : 0.01f * rB;
}

static inline char* ws_take(char*& p, size_t bytes) {
    char* cur = p;
    p += (bytes + 255) & ~(size_t)255;   // keep every buffer 256B-aligned
    return cur;
}

extern "C" void kernel_launch(void* const* d_in, const int* in_sizes, int n_in,
                              void* d_out, int out_size, void* d_ws, size_t ws_size,
                              hipStream_t stream) {
    const float* nodes     = (const float*)d_in[0];
    const float* edges     = (const float*)d_in[1];
    const int*   senders   = (const int*)d_in[2];
    const int*   receivers = (const int*)d_in[3];
    const float* W         = (const float*)d_in[4];
    const float* b         = (const float*)d_in[5];
    const float* attn_W    = (const float*)d_in[6];
    const float* attn_b    = (const float*)d_in[7];
    float* out = (float*)d_out;

    char* p = (char*)d_ws;
    float*  h          = (float*)ws_take(p, sizeof(float) * N_NODES * HID);
    double* z_src      = (double*)ws_take(p, sizeof(double) * N_NODES * N_HEADS);
    double* z_dst      = (double*)ws_take(p, sizeof(double) * N_NODES * N_HEADS);
    int*    counts     = (int*)ws_take(p, sizeof(int) * N_NODES);   // contiguous with
    char*   zpad       = ws_take(p, 256);                           // Ssum: one memset
    double* Ssum       = (double*)zpad;
    int*    srt_padded = (int*)ws_take(p, sizeof(int) * (size_t)N_NODES * MAXDEG);

    // counts (256B-rounded) + the Ssum pad in one memset; srt_padded needs no init
    hipMemsetAsync(counts, 0, ((sizeof(int) * N_NODES + 255) & ~(size_t)255) + 256, stream);

    gemm_hist<<<HBLK + GEMM_BLK, 256, 0, stream>>>(
        nodes, W, b, attn_W, attn_b, edges, h, z_src, z_dst,
        senders, receivers, counts, srt_padded, Ssum);
    node_fused<<<(N_NODES + 7) / 8, 256, 0, stream>>>(
        h, z_src, z_dst, srt_padded, counts, Ssum, out);
}

// Round 8
// 154.396 us; speedup vs baseline: 1.6796x; 1.1402x over previous
//
#include <hip/hip_runtime.h>
#include <math.h>

#define N_NODES 50000
#define N_EDGES 800000
#define IN_DIM 128
#define OUT_DIM 16
#define N_HEADS 4
#define HID 64            // N_HEADS*OUT_DIM
#define AW_COLS 33        // 2*OUT_DIM+1
#define GN 16             // nodes per block (gemm); 3125*16 = 50000 exact
#define GEMM_BLK ((N_NODES + GN - 1) / GN)             // 3125
#define HE 16             // edges per thread (hist)
#define HBLK ((N_EDGES + 256 * HE - 1) / (256 * HE))   // 196
#define MAXDEG 64         // padded bucket width; deg~Poisson(16), max~35 (12 sigma margin)

// LDS plan (R28): phase1 sW 32KB @0 + sN 8KB @32768 = 40960 B.
// phase2 (post-K-loop overlay): scr = 4 sets x 64 lanes x 17 dbl = 34816 B @0,
// h_lds = 4096 B @34816 -> 38912 <= 40960. LDS_Block_Size stays 40960,
// 4 blocks/CU, 16 waves/CU.
#define SMEM_DOUBLES 5120                  // 40960 B
#define SCR_OFF_D 4352                     // 4*64*17 doubles -> h_lds at byte 34816

// R28 = R25 gemm re-anchor + ONE change: PARALLEL k-reduction. R25's w0-only
// sum left 3 waves idle at the barrier (serial section ~4-6us/grid). Now all
// 4 waves dump partials, wave w sums output-quad j==w. Sum order per output
// VERBATIM R25 (b + k[0,8) + k[8,16) + k[16,24) + k[24,32)) -> h,z
// bit-identical. Dump/sum rows 17-dbl padded: 2-way bank alias only (free).
// R27 POST-MORTEM: W-from-global was clean (no spill) but wq's 16-distinct-
// 512B-strided-lines-per-wave-load split into 16 L1 transactions each ->
// gemm 63->84us. Grid-uniform != cheap when per-wave addrs are line-divergent;
// W stays in LDS (both options now measured).
// R26 POST-MORTEM: launch_bounds waves-arg beyond VGPR need -> acc spill,
// +250MB scratch traffic. Keep (256,4) cap=128 >> ~64 used.
// f64 GEMM LOCKED (near-one-hot softmax, argmax flips vs f32 ref).
// NOTE (R7/R8): f64 MFMA produced zeros -- shelved.
// NOTE (R24): more waves without less traffic regresses; don't retry.
__global__ __launch_bounds__(256, 4) void gemm_hist(
    const float* __restrict__ nodes, const float* __restrict__ W,
    const float* __restrict__ b, const float* __restrict__ attn_W,
    const float* __restrict__ attn_b, const float* __restrict__ edges,
    float* __restrict__ h, double* __restrict__ z_src, double* __restrict__ z_dst,
    const int* __restrict__ senders, const int* __restrict__ receivers,
    int* __restrict__ counts, int* __restrict__ srt_padded,
    double* __restrict__ Ssum) {
    __shared__ double smem_d[SMEM_DOUBLES];    // 40960 B, multi-phase overlay
    float* sW = (float*)smem_d;                // 32 KB, rotated-quad layout
    float* sN = (float*)(smem_d + 4096);       // 8 KB @byte 32768, rotated
    int t = threadIdx.x;

    if (blockIdx.x < HBLK) {
        // ---------------- hist + direct bucket-scatter (R17) ----------------
        double* red = smem_d;
        int base = blockIdx.x * 256 * HE + t;
        double sp = 0.0;
        #pragma unroll
        for (int j = 0; j < HE; ++j) {
            int e = base + j * 256;
            if (e < N_EDGES) {
                int r = receivers[e];
                int rank = atomicAdd(&counts[r], 1);            // 0..deg-1
                if (rank < MAXDEG)
                    srt_padded[r * MAXDEG + rank] = senders[e];
                sp += (double)edges[senders[e]];
            }
        }
        red[t] = sp;
        __syncthreads();
        for (int off = 128; off > 0; off >>= 1) {
            if (t < off) red[t] += red[t + off];
            __syncthreads();
        }
        if (t == 0) atomicAdd(Ssum, red[0]);
    } else {
        // -------- gemm body: 4x4 lane tile, 4-way k-split, GN=16 --------
        for (int i4 = t; i4 < HID * IN_DIM / 4; i4 += 256) {   // 2048 quads
            int o = i4 >> 5, kq = i4 & 31;
            float4 v = ((const float4*)W)[i4];
            *(float4*)&sW[o * IN_DIM + (((kq + o) & 31) << 2)] = v;
        }
        int node0 = (blockIdx.x - HBLK) * GN;
        for (int i4 = t; i4 < GN * IN_DIM / 4; i4 += 256) {    // 512 quads, rotated
            int ln = i4 >> 5, kq = i4 & 31;
            float4 v = ((const float4*)nodes)[(long long)(node0 + ln) * (IN_DIM / 4) + kq];
            *(float4*)&sN[ln * IN_DIM + (((kq + ln) & 31) << 2)] = v;
        }
        __syncthreads();                   // barrier 1

        int w = t >> 6, l = t & 63;
        int og = l & 15;                   // outputs og + 16j, j=0..3
        int ng = l >> 4;                   // nodes   ng + 4i,  i=0..3
        int kbase = w * 8;                 // this wave's kq range [kbase, kbase+8)

        double acc[4][4];                  // [j][i]
        #pragma unroll
        for (int j = 0; j < 4; ++j)
            #pragma unroll
            for (int i = 0; i < 4; ++i) acc[j][i] = 0.0;

        #pragma unroll
        for (int s = 0; s < 8; ++s) {
            int kq = kbase + s;
            float4 wq[4], xq[4];
            #pragma unroll
            for (int j = 0; j < 4; ++j) {
                int o = og + 16 * j;
                wq[j] = *(const float4*)&sW[o * IN_DIM + (((kq + o) & 31) << 2)];
            }
            #pragma unroll
            for (int i = 0; i < 4; ++i) {
                int n = ng + 4 * i;
                xq[i] = *(const float4*)&sN[n * IN_DIM + (((kq + n) & 31) << 2)];
            }
            #pragma unroll
            for (int j = 0; j < 4; ++j) {
                double wx = (double)wq[j].x, wy = (double)wq[j].y;
                double wz = (double)wq[j].z, ww = (double)wq[j].w;
                #pragma unroll
                for (int i = 0; i < 4; ++i) {
                    double nx = (double)xq[i].x, ny = (double)xq[i].y;
                    double nz = (double)xq[i].z, nw = (double)xq[i].w;
                    acc[j][i] += wx * nx; acc[j][i] += wy * ny;
                    acc[j][i] += wz * nz; acc[j][i] += ww * nw;
                }
            }
        }
        __syncthreads();                   // barrier 2: sW/sN reads done

        // ---- PARALLEL k-reduction: all waves dump, wave w sums quad j=w ----
        double* scr = smem_d;              // overlays dead sW/sN; 34816 B
        float* h_lds = (float*)(smem_d + SCR_OFF_D);   // 4 KB @byte 34816
        {
            double* dst = &scr[(w * 64 + l) * 17];
            #pragma unroll
            for (int j = 0; j < 4; ++j)
                #pragma unroll
                for (int i = 0; i < 4; ++i) dst[j * 4 + i] = acc[j][i];
        }
        __syncthreads();                   // barrier 3
        {
            int jw = w;                    // this wave finalizes outputs og+16w
            double bj = (double)b[og + 16 * jw];
            #pragma unroll
            for (int i = 0; i < 4; ++i) {
                double sum = bj;
                sum += scr[(0 * 64 + l) * 17 + jw * 4 + i];   // k[0,8)
                sum += scr[(1 * 64 + l) * 17 + jw * 4 + i];   // k[8,16)
                sum += scr[(2 * 64 + l) * 17 + jw * 4 + i];   // k[16,24)
                sum += scr[(3 * 64 + l) * 17 + jw * 4 + i];   // k[24,32)
                h_lds[(ng + 4 * i) * HID + og + 16 * jw] = (float)sum;
            }
        }
        __syncthreads();                   // barrier 4

        // ---- epilogue: R21 layout/order verbatim, h values from h_lds ----
        int half = l >> 5;
        int o2 = l & 31;
        int nwbase = w * 4 + half * 2;
        int hd0 = o2 >> 4, d = o2 & 15;
        int hd1 = hd0 + 2;
        double aw00 = (double)attn_W[hd0 * AW_COLS + d];
        double aw01 = (double)attn_W[hd0 * AW_COLS + OUT_DIM + d];
        double aw10 = (double)attn_W[hd1 * AW_COLS + d];
        double aw11 = (double)attn_W[hd1 * AW_COLS + OUT_DIM + d];
        double wE0 = (double)attn_W[hd0 * AW_COLS + 2 * OUT_DIM];
        double wE1 = (double)attn_W[hd1 * AW_COLS + 2 * OUT_DIM];
        double bb0 = (double)attn_b[hd0], bb1 = (double)attn_b[hd1];
        #pragma unroll
        for (int j = 0; j < 2; ++j) {
            int nl = nwbase + j;
            int n = node0 + nl;            // always < 50000 (exact tiling)
            float hf0 = h_lds[nl * HID + o2];
            float hf1 = h_lds[nl * HID + o2 + 32];
            double c00 = (double)hf0 * aw00;   // a_src part, head hd0
            double c01 = (double)hf0 * aw01;   // a_dst part, head hd0
            double c10 = (double)hf1 * aw10;   // a_src part, head hd1
            double c11 = (double)hf1 * aw11;   // a_dst part, head hd1
            #pragma unroll
            for (int k = 1; k <= 8; k <<= 1) {
                c00 += __shfl_xor(c00, k, 64);
                c01 += __shfl_xor(c01, k, 64);
                c10 += __shfl_xor(c10, k, 64);
                c11 += __shfl_xor(c11, k, 64);
            }
            if (d == 0) {
                double se = (double)edges[n];
                z_src[n * N_HEADS + hd0] = c00 + se * wE0;
                z_dst[n * N_HEADS + hd0] = c01 + bb0;
                z_src[n * N_HEADS + hd1] = c10 + se * wE1;
                z_dst[n * N_HEADS + hd1] = c11 + bb1;
            }
        }
        // coalesced h write: block's h region is contiguous (1024 floats)
        ((float4*)h)[(long long)node0 * (HID / 4) + t] = ((const float4*)h_lds)[t];
    }
}

// R22 form (best known, FROZEN). TWO nodes per wave, phases pairwise
// interleaved; near-one-hot softmax -> ballot loop does ~1-4 gathers/node
// (R23's dense rewrite did 16x traffic, +12us -- don't retry).
__global__ __launch_bounds__(256, 8) void node_fused(
    const float* __restrict__ h, const double* __restrict__ z_src,
    const double* __restrict__ z_dst,
    const int* __restrict__ srt_padded, const int* __restrict__ counts,
    const double* __restrict__ Ssum, float* __restrict__ out) {
    int w = threadIdx.x >> 6;
    int lane = threadIdx.x & 63;
    int nA = blockIdx.x * 8 + w * 2;     // grid exact: 6250*8 = 50000
    int nB = nA + 1;
    int hd = lane >> 4, q = lane & 15;

    int degA = counts[nA]; if (degA > MAXDEG) degA = MAXDEG;
    int degB = counts[nB]; if (degB > MAXDEG) degB = MAXDEG;
    double S = 4.0 * Ssum[0];                       // sent_e tiled over heads
    double zdA = z_dst[nA * N_HEADS + hd];
    double zdB = z_dst[nB * N_HEADS + hd];

    // ---- edge-id gather (both nodes issued before use) ----
    int sA[4], sB[4];
    #pragma unroll
    for (int j = 0; j < 4; ++j) {
        int ei = q + 16 * j;
        sA[j] = (ei < degA) ? srt_padded[nA * MAXDEG + ei] : 0;
        sB[j] = (ei < degB) ? srt_padded[nB * MAXDEG + ei] : 0;
    }
    // ---- z_src scatter-gather + leaky (f64, then round) — bit-exact ----
    float yA[4], yB[4];
    #pragma unroll
    for (int j = 0; j < 4; ++j) {
        int ei = q + 16 * j;
        yA[j] = -INFINITY;
        yB[j] = -INFINITY;
        if (ei < degA) {
            double yy = z_src[sA[j] * N_HEADS + hd] + zdA;
            yy = yy > 0.0 ? yy : 0.01 * yy;
            yA[j] = (float)yy;
        }
        if (ei < degB) {
            double yy = z_src[sB[j] * N_HEADS + hd] + zdB;
            yy = yy > 0.0 ? yy : 0.01 * yy;
            yB[j] = (float)yy;
        }
    }
    // ---- per-head max: two butterfly chains interleaved ----
    float mA = fmaxf(fmaxf(yA[0], yA[1]), fmaxf(yA[2], yA[3]));
    float mB = fmaxf(fmaxf(yB[0], yB[1]), fmaxf(yB[2], yB[3]));
    #pragma unroll
    for (int k = 1; k <= 8; k <<= 1) {
        mA = fmaxf(mA, __shfl_xor(mA, k, 64));
        mB = fmaxf(mB, __shfl_xor(mB, k, 64));
    }
    // ---- exp + denominator (same expression order as R21) ----
    float evA[4], evB[4];
    float dA = 0.f, dB = 0.f;
    #pragma unroll
    for (int j = 0; j < 4; ++j) {
        evA[j] = (yA[j] == -INFINITY) ? 0.f
               : __expf((float)(S * ((double)yA[j] - (double)mA)));
        dA += evA[j];
        evB[j] = (yB[j] == -INFINITY) ? 0.f
               : __expf((float)(S * ((double)yB[j] - (double)mB)));
        dB += evB[j];
    }
    #pragma unroll
    for (int k = 1; k <= 8; k <<= 1) {
        dA += __shfl_xor(dA, k, 64);
        dB += __shfl_xor(dB, k, 64);
    }
    // ---- ballot-compressed accumulate, node A then node B (order preserved) ----
    float accA = 0.f;
    #pragma unroll
    for (int j = 0; j < 4; ++j) {
        unsigned long long mk = __ballot(evA[j] != 0.f);
        unsigned um = (unsigned)((mk | (mk >> 16) | (mk >> 32) | (mk >> 48)) & 0xFFFFull);
        while (um) {
            int qq = __builtin_ctz(um);
            um &= um - 1;
            int src = (lane & 48) | qq;                 // own head's copy
            float evv = __shfl(evA[j], src, 64);
            int sj = __shfl(sA[j], src, 64);
            if (evv != 0.f)
                accA = fmaf(evv, h[sj * HID + lane], accA);
        }
    }
    float accB = 0.f;
    #pragma unroll
    for (int j = 0; j < 4; ++j) {
        unsigned long long mk = __ballot(evB[j] != 0.f);
        unsigned um = (unsigned)((mk | (mk >> 16) | (mk >> 32) | (mk >> 48)) & 0xFFFFull);
        while (um) {
            int qq = __builtin_ctz(um);
            um &= um - 1;
            int src = (lane & 48) | qq;
            float evv = __shfl(evB[j], src, 64);
            int sj = __shfl(sB[j], src, 64);
            if (evv != 0.f)
                accB = fmaf(evv, h[sj * HID + lane], accB);
        }
    }
    float rA = (dA > 0.f) ? accA / dA : 0.f;
    float rB = (dB > 0.f) ? accB / dB : 0.f;
    out[nA * HID + lane] = rA > 0.f ? rA : 0.01f * rA;
    out[nB * HID + lane] = rB > 0.f ? rB : 0.01f * rB;
}

static inline char* ws_take(char*& p, size_t bytes) {
    char* cur = p;
    p += (bytes + 255) & ~(size_t)255;   // keep every buffer 256B-aligned
    return cur;
}

extern "C" void kernel_launch(void* const* d_in, const int* in_sizes, int n_in,
                              void* d_out, int out_size, void* d_ws, size_t ws_size,
                              hipStream_t stream) {
    const float* nodes     = (const float*)d_in[0];
    const float* edges     = (const float*)d_in[1];
    const int*   senders   = (const int*)d_in[2];
    const int*   receivers = (const int*)d_in[3];
    const float* W         = (const float*)d_in[4];
    const float* b         = (const float*)d_in[5];
    const float* attn_W    = (const float*)d_in[6];
    const float* attn_b    = (const float*)d_in[7];
    float* out = (float*)d_out;

    char* p = (char*)d_ws;
    float*  h          = (float*)ws_take(p, sizeof(float) * N_NODES * HID);
    double* z_src      = (double*)ws_take(p, sizeof(double) * N_NODES * N_HEADS);
    double* z_dst      = (double*)ws_take(p, sizeof(double) * N_NODES * N_HEADS);
    int*    counts     = (int*)ws_take(p, sizeof(int) * N_NODES);   // contiguous with
    char*   zpad       = ws_take(p, 256);                           // Ssum: one memset
    double* Ssum       = (double*)zpad;
    int*    srt_padded = (int*)ws_take(p, sizeof(int) * (size_t)N_NODES * MAXDEG);

    // counts (256B-rounded) + the Ssum pad in one memset; srt_padded needs no init
    hipMemsetAsync(counts, 0, ((sizeof(int) * N_NODES + 255) & ~(size_t)255) + 256, stream);

    gemm_hist<<<HBLK + GEMM_BLK, 256, 0, stream>>>(
        nodes, W, b, attn_W, attn_b, edges, h, z_src, z_dst,
        senders, receivers, counts, srt_padded, Ssum);
    node_fused<<<(N_NODES + 7) / 8, 256, 0, stream>>>(
        h, z_src, z_dst, srt_padded, counts, Ssum, out);
}